// Round 1
// baseline (1176.514 us; speedup 1.0000x reference)
//
#include <hip/hip_runtime.h>

#define S_ 4096
#define E_ 16
#define K_ 2
#define D_ 1024
#define H_ 2816
#define MAXT 80
#define MP_ (MAXT * 128)

// meta int indices (in ws, zeroed each launch)
#define ME_CNT   0
#define ME_FILL  16
#define ME_POFF  32
#define ME_NT    48
#define ME_TE    64
#define ME_TR    (64 + MAXT)

// ws layout (bytes)
#define WS_META   0
#define WS_SLOT   4096                    // 8192 ints
#define WS_RW     36864                   // 8192 floats
#define WS_TOPI   69632                   // 8192 ints
#define WS_XS     (1u << 20)              // bf16 [MP_, D_]  (re-used as y fp32 [MP_, D_])
#define WS_H      (WS_XS + (size_t)MP_ * D_ * 4)  // bf16 [MP_, H_]

typedef float floatx4 __attribute__((ext_vector_type(4)));
typedef __bf16 bf16x8 __attribute__((ext_vector_type(8)));

__device__ __forceinline__ unsigned short f2bf(float f) {
  unsigned u = __float_as_uint(f);
  u += 0x7fffu + ((u >> 16) & 1u);   // RNE
  return (unsigned short)(u >> 16);
}
__device__ __forceinline__ unsigned pack2(float a, float b) {
  return (unsigned)f2bf(a) | ((unsigned)f2bf(b) << 16);
}

// ---------------- router: logits, softmax, top-2, weights ----------------
__global__ __launch_bounds__(256) void router_k(
    const float* __restrict__ x, const float* __restrict__ gw,
    float* __restrict__ logits_out, float* __restrict__ topi_out,
    float* __restrict__ rw, int* __restrict__ topi, int* __restrict__ meta)
{
  int s = blockIdx.x;
  int t = threadIdx.x;
  __shared__ float xl[D_];
  __shared__ float red[E_][16];
  __shared__ float lg[E_];
  for (int d = t; d < D_; d += 256) xl[d] = x[(size_t)s * D_ + d];
  __syncthreads();
  int e = t >> 4, i = t & 15;
  const float* g = gw + e * D_;
  float p = 0.f;
  for (int j = 0; j < 64; ++j) p += xl[i + 16 * j] * g[i + 16 * j];
  red[e][i] = p;
  __syncthreads();
  if (t < E_) {
    float sm = 0.f;
    for (int j = 0; j < 16; ++j) sm += red[t][j];
    lg[t] = sm;
    logits_out[(size_t)s * E_ + t] = sm;
  }
  __syncthreads();
  if (t == 0) {
    float mx = lg[0];
    for (int j = 1; j < E_; ++j) mx = fmaxf(mx, lg[j]);
    float pr[E_];
    for (int j = 0; j < E_; ++j) pr[j] = expf(lg[j] - mx);
    int i0 = 0; float b0 = pr[0];
    for (int j = 1; j < E_; ++j) if (pr[j] > b0) { b0 = pr[j]; i0 = j; }
    int i1 = -1; float b1 = -1.f;
    for (int j = 0; j < E_; ++j) if (j != i0 && pr[j] > b1) { b1 = pr[j]; i1 = j; }
    float w0 = b0 / (b0 + b1), w1 = b1 / (b0 + b1);
    topi_out[(size_t)s * K_ + 0] = (float)i0;
    topi_out[(size_t)s * K_ + 1] = (float)i1;
    rw[s * K_ + 0] = w0; rw[s * K_ + 1] = w1;
    topi[s * K_ + 0] = i0; topi[s * K_ + 1] = i1;
    atomicAdd(&meta[ME_CNT + i0], 1);
    atomicAdd(&meta[ME_CNT + i1], 1);
  }
}

// ---------------- scan: padded offsets + tile map ----------------
__global__ void scan_k(int* __restrict__ meta) {
  if (threadIdx.x == 0 && blockIdx.x == 0) {
    int off = 0, nt = 0;
    for (int e = 0; e < E_; ++e) {
      meta[ME_POFF + e] = off;
      int c = meta[ME_CNT + e];
      int tiles = (c + 127) >> 7;
      for (int i = 0; i < tiles; ++i) { meta[ME_TE + nt] = e; meta[ME_TR + nt] = off + i * 128; ++nt; }
      off += tiles << 7;
    }
    meta[ME_NT] = nt;
  }
}

// ---------------- scatter: assign each (s,k) a slot in its expert region ----------------
__global__ __launch_bounds__(256) void scatter_k(
    const int* __restrict__ topi, int* __restrict__ meta, int* __restrict__ slot_of)
{
  int idx = blockIdx.x * 256 + threadIdx.x;
  if (idx >= S_ * K_) return;
  int e = topi[idx];
  int pos = meta[ME_POFF + e] + atomicAdd(&meta[ME_FILL + e], 1);
  slot_of[idx] = pos;
}

// ---------------- gather: xs[slot] = bf16(hidden[s]) ----------------
__global__ __launch_bounds__(256) void gather_k(
    const float* __restrict__ x, const int* __restrict__ slot_of,
    unsigned short* __restrict__ xs)
{
  int idx = blockIdx.x;
  int s = idx >> 1;
  int pos = slot_of[idx];
  int t = threadIdx.x;
  float4 v = ((const float4*)(x + (size_t)s * D_))[t];
  ((uint2*)(xs + (size_t)pos * D_))[t] = make_uint2(pack2(v.x, v.y), pack2(v.z, v.w));
}

// ---------------- GEMM1: h = bf16( silu(xs@Wg^T) * (xs@Wu^T) ) ----------------
// 128x128 tile, BK=32, 4 waves (2x2), 16x16x32 bf16 MFMA, dual accumulators.
__global__ __launch_bounds__(256) void gemm1_k(
    const unsigned short* __restrict__ xs,
    const float* __restrict__ wg, const float* __restrict__ wu,
    unsigned short* __restrict__ h, const int* __restrict__ meta)
{
  int tile = blockIdx.x;
  if (tile >= meta[ME_NT]) return;
  int ntile = blockIdx.y;
  int e = meta[ME_TE + tile];
  int row0 = meta[ME_TR + tile];

  __shared__ uint4 As4[512];  // 128 x 32 bf16
  __shared__ uint4 Bg4[512];
  __shared__ uint4 Bu4[512];
  const unsigned short* As = (const unsigned short*)As4;
  const unsigned short* Bg = (const unsigned short*)Bg4;
  const unsigned short* Bu = (const unsigned short*)Bu4;

  int t = threadIdx.x;
  int lane = t & 63, w = t >> 6;
  int wm = w >> 1, wn = w & 1;

  const unsigned short* ap = xs + (size_t)row0 * D_;
  const float* wgp = wg + ((size_t)e * H_ + ntile * 128) * D_;
  const float* wup = wu + ((size_t)e * H_ + ntile * 128) * D_;

  floatx4 zero4 = {0.f, 0.f, 0.f, 0.f};
  floatx4 accg[4][4], accu[4][4];
  for (int a = 0; a < 4; ++a) for (int b = 0; b < 4; ++b) { accg[a][b] = zero4; accu[a][b] = zero4; }

  int bn = t >> 1, bkh = t & 1;

  for (int k0 = 0; k0 < D_; k0 += 32) {
    __syncthreads();
    {
      int c = t;
      As4[c] = *(const uint4*)(ap + (size_t)(c >> 2) * D_ + k0 + (c & 3) * 8);
      c = t + 256;
      As4[c] = *(const uint4*)(ap + (size_t)(c >> 2) * D_ + k0 + (c & 3) * 8);
    }
    {
      const float4* srcg = (const float4*)(wgp + (size_t)bn * D_ + k0 + bkh * 16);
      const float4* srcu = (const float4*)(wup + (size_t)bn * D_ + k0 + bkh * 16);
      float4 g0 = srcg[0], g1 = srcg[1], g2 = srcg[2], g3 = srcg[3];
      float4 u0 = srcu[0], u1 = srcu[1], u2 = srcu[2], u3 = srcu[3];
      int base = bn * 4 + bkh * 2;
      Bg4[base]     = make_uint4(pack2(g0.x, g0.y), pack2(g0.z, g0.w), pack2(g1.x, g1.y), pack2(g1.z, g1.w));
      Bg4[base + 1] = make_uint4(pack2(g2.x, g2.y), pack2(g2.z, g2.w), pack2(g3.x, g3.y), pack2(g3.z, g3.w));
      Bu4[base]     = make_uint4(pack2(u0.x, u0.y), pack2(u0.z, u0.w), pack2(u1.x, u1.y), pack2(u1.z, u1.w));
      Bu4[base + 1] = make_uint4(pack2(u2.x, u2.y), pack2(u2.z, u2.w), pack2(u3.x, u3.y), pack2(u3.z, u3.w));
    }
    __syncthreads();
    int mrow = lane & 15;
    int kq = (lane >> 4) * 8;
    bf16x8 af[4], bg[4], bu[4];
    for (int mi = 0; mi < 4; ++mi)
      af[mi] = *(const bf16x8*)(As + (wm * 64 + mi * 16 + mrow) * 32 + kq);
    for (int ni = 0; ni < 4; ++ni) {
      int r = (wn * 64 + ni * 16 + mrow) * 32 + kq;
      bg[ni] = *(const bf16x8*)(Bg + r);
      bu[ni] = *(const bf16x8*)(Bu + r);
    }
    for (int mi = 0; mi < 4; ++mi)
      for (int ni = 0; ni < 4; ++ni) {
        accg[mi][ni] = __builtin_amdgcn_mfma_f32_16x16x32_bf16(af[mi], bg[ni], accg[mi][ni], 0, 0, 0);
        accu[mi][ni] = __builtin_amdgcn_mfma_f32_16x16x32_bf16(af[mi], bu[ni], accu[mi][ni], 0, 0, 0);
      }
  }
  int colb = ntile * 128 + wn * 64;
  int rquad = (lane >> 4) * 4;
  for (int mi = 0; mi < 4; ++mi)
    for (int ni = 0; ni < 4; ++ni)
      for (int r = 0; r < 4; ++r) {
        int row = row0 + wm * 64 + mi * 16 + rquad + r;
        int col = colb + ni * 16 + (lane & 15);
        float gv = accg[mi][ni][r], uv = accu[mi][ni][r];
        float sv = gv / (1.f + expf(-gv));
        h[(size_t)row * H_ + col] = f2bf(sv * uv);
      }
}

// ---------------- GEMM2: y = h @ Wd^T  (fp32 out) ----------------
__global__ __launch_bounds__(256) void gemm2_k(
    const unsigned short* __restrict__ hbuf,
    const float* __restrict__ wd,
    float* __restrict__ y, const int* __restrict__ meta)
{
  int tile = blockIdx.x;
  if (tile >= meta[ME_NT]) return;
  int ntile = blockIdx.y;  // 0..7 over D_=1024 cols
  int e = meta[ME_TE + tile];
  int row0 = meta[ME_TR + tile];

  __shared__ uint4 As4[512];
  __shared__ uint4 Bd4[512];
  const unsigned short* As = (const unsigned short*)As4;
  const unsigned short* Bd = (const unsigned short*)Bd4;

  int t = threadIdx.x;
  int lane = t & 63, w = t >> 6;
  int wm = w >> 1, wn = w & 1;

  const unsigned short* ap = hbuf + (size_t)row0 * H_;
  const float* wdp = wd + ((size_t)e * D_ + ntile * 128) * H_;

  floatx4 zero4 = {0.f, 0.f, 0.f, 0.f};
  floatx4 acc[4][4];
  for (int a = 0; a < 4; ++a) for (int b = 0; b < 4; ++b) acc[a][b] = zero4;

  int bn = t >> 1, bkh = t & 1;

  for (int k0 = 0; k0 < H_; k0 += 32) {
    __syncthreads();
    {
      int c = t;
      As4[c] = *(const uint4*)(ap + (size_t)(c >> 2) * H_ + k0 + (c & 3) * 8);
      c = t + 256;
      As4[c] = *(const uint4*)(ap + (size_t)(c >> 2) * H_ + k0 + (c & 3) * 8);
    }
    {
      const float4* srcd = (const float4*)(wdp + (size_t)bn * H_ + k0 + bkh * 16);
      float4 d0 = srcd[0], d1 = srcd[1], d2 = srcd[2], d3 = srcd[3];
      int base = bn * 4 + bkh * 2;
      Bd4[base]     = make_uint4(pack2(d0.x, d0.y), pack2(d0.z, d0.w), pack2(d1.x, d1.y), pack2(d1.z, d1.w));
      Bd4[base + 1] = make_uint4(pack2(d2.x, d2.y), pack2(d2.z, d2.w), pack2(d3.x, d3.y), pack2(d3.z, d3.w));
    }
    __syncthreads();
    int mrow = lane & 15;
    int kq = (lane >> 4) * 8;
    bf16x8 af[4], bf[4];
    for (int mi = 0; mi < 4; ++mi)
      af[mi] = *(const bf16x8*)(As + (wm * 64 + mi * 16 + mrow) * 32 + kq);
    for (int ni = 0; ni < 4; ++ni)
      bf[ni] = *(const bf16x8*)(Bd + (wn * 64 + ni * 16 + mrow) * 32 + kq);
    for (int mi = 0; mi < 4; ++mi)
      for (int ni = 0; ni < 4; ++ni)
        acc[mi][ni] = __builtin_amdgcn_mfma_f32_16x16x32_bf16(af[mi], bf[ni], acc[mi][ni], 0, 0, 0);
  }
  int colb = ntile * 128 + wn * 64;
  int rquad = (lane >> 4) * 4;
  for (int mi = 0; mi < 4; ++mi)
    for (int ni = 0; ni < 4; ++ni)
      for (int r = 0; r < 4; ++r) {
        int row = row0 + wm * 64 + mi * 16 + rquad + r;
        int col = colb + ni * 16 + (lane & 15);
        y[(size_t)row * D_ + col] = acc[mi][ni][r];
      }
}

// ---------------- combine: out[s] = w0*y[slot0] + w1*y[slot1] ----------------
__global__ __launch_bounds__(256) void combine_k(
    const float* __restrict__ y, const float* __restrict__ rw,
    const int* __restrict__ slot_of, float* __restrict__ out)
{
  int s = blockIdx.x, t = threadIdx.x;
  int s0 = slot_of[s * 2], s1 = slot_of[s * 2 + 1];
  float w0 = rw[s * 2], w1 = rw[s * 2 + 1];
  float4 a = ((const float4*)(y + (size_t)s0 * D_))[t];
  float4 b = ((const float4*)(y + (size_t)s1 * D_))[t];
  float4 o;
  o.x = w0 * a.x + w1 * b.x;
  o.y = w0 * a.y + w1 * b.y;
  o.z = w0 * a.z + w1 * b.z;
  o.w = w0 * a.w + w1 * b.w;
  ((float4*)(out + (size_t)s * D_))[t] = o;
}

extern "C" void kernel_launch(void* const* d_in, const int* in_sizes, int n_in,
                              void* d_out, int out_size, void* d_ws, size_t ws_size,
                              hipStream_t stream) {
  const float* x  = (const float*)d_in[0];
  const float* gw = (const float*)d_in[1];
  const float* wg = (const float*)d_in[2];
  const float* wu = (const float*)d_in[3];
  const float* wd = (const float*)d_in[4];

  float* out = (float*)d_out;
  float* logits_out = out + (size_t)S_ * D_;
  float* topi_out = logits_out + (size_t)S_ * E_;

  char* ws = (char*)d_ws;
  int* meta = (int*)(ws + WS_META);
  int* slot_of = (int*)(ws + WS_SLOT);
  float* rw = (float*)(ws + WS_RW);
  int* topi = (int*)(ws + WS_TOPI);
  unsigned short* xs = (unsigned short*)(ws + WS_XS);
  float* y = (float*)(ws + WS_XS);            // overlays xs (dead after gemm1)
  unsigned short* h = (unsigned short*)(ws + WS_H);

  hipMemsetAsync(meta, 0, 4096, stream);
  hipMemsetAsync(xs, 0, (size_t)MP_ * D_ * 2, stream);  // zero pad rows

  router_k<<<S_, 256, 0, stream>>>(x, gw, logits_out, topi_out, rw, topi, meta);
  scan_k<<<1, 64, 0, stream>>>(meta);
  scatter_k<<<(S_ * K_ + 255) / 256, 256, 0, stream>>>(topi, meta, slot_of);
  gather_k<<<S_ * K_, 256, 0, stream>>>(x, slot_of, xs);
  gemm1_k<<<dim3(MAXT, H_ / 128), 256, 0, stream>>>(xs, wg, wu, h, meta);
  gemm2_k<<<dim3(MAXT, D_ / 128), 256, 0, stream>>>(h, wd, y, meta);
  combine_k<<<S_, 256, 0, stream>>>(y, rw, slot_of, out);
}

// Round 2
// 1020.079 us; speedup vs baseline: 1.1534x; 1.1534x over previous
//
#include <hip/hip_runtime.h>

#define S_ 4096
#define E_ 16
#define K_ 2
#define D_ 1024
#define H_ 2816
#define H2_ (2 * H_)
#define MAXT 80
#define MP_ (MAXT * 128)

// meta int indices (in ws, zeroed each launch)
#define ME_CNT   0
#define ME_FILL  16
#define ME_POFF  32
#define ME_NT    48
#define ME_TE    64
#define ME_TR    (64 + MAXT)

// ws layout (bytes)
#define WS_META   0
#define WS_SLOT   4096                    // 8192 ints
#define WS_RW     36864                   // 8192 floats
#define WS_TOPI   69632                   // 8192 ints
#define WS_XS     (1u << 20)              // bf16 [MP_, D_]  (re-used as y fp32 [MP_, D_])
#define WS_H      (WS_XS + (size_t)MP_ * D_ * 4)   // bf16 [MP_, H_]
#define WS_W      (WS_H + (size_t)MP_ * H_ * 2)    // bf16 weights: W1 [E][2H][D], later W2 [E][D][H]
#define WS_NEED   (WS_W + (size_t)E_ * H2_ * D_ * 2)

typedef float floatx4 __attribute__((ext_vector_type(4)));
typedef __bf16 bf16x8 __attribute__((ext_vector_type(8)));

__device__ __forceinline__ unsigned short f2bf(float f) {
  unsigned u = __float_as_uint(f);
  u += 0x7fffu + ((u >> 16) & 1u);   // RNE
  return (unsigned short)(u >> 16);
}
__device__ __forceinline__ unsigned pack2(float a, float b) {
  return (unsigned)f2bf(a) | ((unsigned)f2bf(b) << 16);
}
__device__ __forceinline__ void gl_lds16(const unsigned short* g, unsigned short* l) {
  __builtin_amdgcn_global_load_lds(
      (const __attribute__((address_space(1))) unsigned int*)g,
      (__attribute__((address_space(3))) unsigned int*)l, 16, 0, 0);
}

// ---------------- router: logits, softmax, top-2, weights ----------------
__global__ __launch_bounds__(256) void router_k(
    const float* __restrict__ x, const float* __restrict__ gw,
    float* __restrict__ logits_out, float* __restrict__ topi_out,
    float* __restrict__ rw, int* __restrict__ topi, int* __restrict__ meta)
{
  int s = blockIdx.x;
  int t = threadIdx.x;
  __shared__ float xl[D_];
  __shared__ float red[E_][16];
  __shared__ float lg[E_];
  for (int d = t; d < D_; d += 256) xl[d] = x[(size_t)s * D_ + d];
  __syncthreads();
  int e = t >> 4, i = t & 15;
  const float* g = gw + e * D_;
  float p = 0.f;
  for (int j = 0; j < 64; ++j) p += xl[i + 16 * j] * g[i + 16 * j];
  red[e][i] = p;
  __syncthreads();
  if (t < E_) {
    float sm = 0.f;
    for (int j = 0; j < 16; ++j) sm += red[t][j];
    lg[t] = sm;
    logits_out[(size_t)s * E_ + t] = sm;
  }
  __syncthreads();
  if (t == 0) {
    float mx = lg[0];
    for (int j = 1; j < E_; ++j) mx = fmaxf(mx, lg[j]);
    float pr[E_];
    for (int j = 0; j < E_; ++j) pr[j] = expf(lg[j] - mx);
    int i0 = 0; float b0 = pr[0];
    for (int j = 1; j < E_; ++j) if (pr[j] > b0) { b0 = pr[j]; i0 = j; }
    int i1 = -1; float b1 = -1.f;
    for (int j = 0; j < E_; ++j) if (j != i0 && pr[j] > b1) { b1 = pr[j]; i1 = j; }
    float w0 = b0 / (b0 + b1), w1 = b1 / (b0 + b1);
    topi_out[(size_t)s * K_ + 0] = (float)i0;
    topi_out[(size_t)s * K_ + 1] = (float)i1;
    rw[s * K_ + 0] = w0; rw[s * K_ + 1] = w1;
    topi[s * K_ + 0] = i0; topi[s * K_ + 1] = i1;
    atomicAdd(&meta[ME_CNT + i0], 1);
    atomicAdd(&meta[ME_CNT + i1], 1);
  }
}

// ---------------- scan: padded offsets + tile map ----------------
__global__ void scan_k(int* __restrict__ meta) {
  if (threadIdx.x == 0 && blockIdx.x == 0) {
    int off = 0, nt = 0;
    for (int e = 0; e < E_; ++e) {
      meta[ME_POFF + e] = off;
      int c = meta[ME_CNT + e];
      int tiles = (c + 127) >> 7;
      for (int i = 0; i < tiles; ++i) { meta[ME_TE + nt] = e; meta[ME_TR + nt] = off + i * 128; ++nt; }
      off += tiles << 7;
    }
    meta[ME_NT] = nt;
  }
}

// ---------------- scatter ----------------
__global__ __launch_bounds__(256) void scatter_k(
    const int* __restrict__ topi, int* __restrict__ meta, int* __restrict__ slot_of)
{
  int idx = blockIdx.x * 256 + threadIdx.x;
  if (idx >= S_ * K_) return;
  int e = topi[idx];
  int pos = meta[ME_POFF + e] + atomicAdd(&meta[ME_FILL + e], 1);
  slot_of[idx] = pos;
}

// ---------------- gather: xs[slot] = bf16(hidden[s]) ----------------
__global__ __launch_bounds__(256) void gather_k(
    const float* __restrict__ x, const int* __restrict__ slot_of,
    unsigned short* __restrict__ xs)
{
  int idx = blockIdx.x;
  int s = idx >> 1;
  int pos = slot_of[idx];
  int t = threadIdx.x;
  float4 v = ((const float4*)(x + (size_t)s * D_))[t];
  ((uint2*)(xs + (size_t)pos * D_))[t] = make_uint2(pack2(v.x, v.y), pack2(v.z, v.w));
}

// ---------------- convert: W1[e][2j+(0:g,1:u)][d] = bf16(wg/wu[e][j][d]) ----------------
__global__ __launch_bounds__(128) void convert_gu_k(
    const float* __restrict__ wg, const float* __restrict__ wu,
    unsigned short* __restrict__ W1)
{
  int r = blockIdx.x;   // 0..5631
  int e = blockIdx.y;   // 0..15
  int j = r >> 1;
  const float* src = ((r & 1) ? wu : wg) + ((size_t)e * H_ + j) * D_;
  unsigned short* dst = W1 + ((size_t)e * H2_ + r) * D_;
  int t = threadIdx.x;
  float4 a = ((const float4*)src)[2 * t];
  float4 b = ((const float4*)src)[2 * t + 1];
  ((uint4*)dst)[t] = make_uint4(pack2(a.x, a.y), pack2(a.z, a.w),
                                pack2(b.x, b.y), pack2(b.z, b.w));
}

// ---------------- convert: W2 = bf16(wd), same layout ----------------
__global__ __launch_bounds__(256) void convert_d_k(
    const float* __restrict__ wd, unsigned short* __restrict__ W2)
{
  size_t i = (size_t)blockIdx.x * 256 + threadIdx.x;
  float4 a = ((const float4*)wd)[2 * i];
  float4 b = ((const float4*)wd)[2 * i + 1];
  ((uint4*)W2)[i] = make_uint4(pack2(a.x, a.y), pack2(a.z, a.w),
                               pack2(b.x, b.y), pack2(b.z, b.w));
}

// ---------------- GEMM1 (fast): h = SwiGLU(xs @ W1^T), W1 gate/up interleaved ----------------
// 128x128 tile, BK=64, global_load_lds 16B staging, 16x16x32 bf16 MFMA.
__global__ __launch_bounds__(256) void gemm1_f(
    const unsigned short* __restrict__ xs, const unsigned short* __restrict__ W1,
    unsigned short* __restrict__ h, const int* __restrict__ meta)
{
  int tile = blockIdx.x;
  if (tile >= meta[ME_NT]) return;
  int ntile = blockIdx.y;  // 0..43 over 2H
  int e = meta[ME_TE + tile];
  int row0 = meta[ME_TR + tile];

  __shared__ unsigned short As[128 * 64];
  __shared__ unsigned short Bs[128 * 64];

  int t = threadIdx.x, lane = t & 63, w = t >> 6;
  int wm = w >> 1, wn = w & 1;

  const unsigned short* ap = xs + ((size_t)row0 + w * 32 + (lane >> 3)) * D_ + (lane & 7) * 8;
  const unsigned short* bp = W1 + ((size_t)e * H2_ + ntile * 128 + w * 32 + (lane >> 3)) * D_ + (lane & 7) * 8;
  unsigned short* la = As + (w * 32) * 64;
  unsigned short* lb = Bs + (w * 32) * 64;

  floatx4 acc[4][4];
  floatx4 zero4 = {0.f, 0.f, 0.f, 0.f};
#pragma unroll
  for (int a = 0; a < 4; ++a)
#pragma unroll
    for (int b = 0; b < 4; ++b) acc[a][b] = zero4;

  int mrow = lane & 15, kq = (lane >> 4) * 8;

  for (int k0 = 0; k0 < D_; k0 += 64) {
    __syncthreads();
#pragma unroll
    for (int i = 0; i < 4; ++i) {
      gl_lds16(ap + k0 + i * 8 * D_, la + i * 8 * 64);
      gl_lds16(bp + k0 + i * 8 * D_, lb + i * 8 * 64);
    }
    __syncthreads();
#pragma unroll
    for (int kk = 0; kk < 64; kk += 32) {
      bf16x8 af[4], bfv[4];
#pragma unroll
      for (int mi = 0; mi < 4; ++mi)
        af[mi] = *(const bf16x8*)(As + (wm * 64 + mi * 16 + mrow) * 64 + kk + kq);
#pragma unroll
      for (int ni = 0; ni < 4; ++ni)
        bfv[ni] = *(const bf16x8*)(Bs + (wn * 64 + ni * 16 + mrow) * 64 + kk + kq);
#pragma unroll
      for (int mi = 0; mi < 4; ++mi)
#pragma unroll
        for (int ni = 0; ni < 4; ++ni)
          acc[mi][ni] = __builtin_amdgcn_mfma_f32_16x16x32_bf16(af[mi], bfv[ni], acc[mi][ni], 0, 0, 0);
    }
  }

  int rquad = (lane >> 4) * 4;
  int colb = ntile * 128 + wn * 64;
#pragma unroll
  for (int mi = 0; mi < 4; ++mi)
#pragma unroll
    for (int ni = 0; ni < 4; ++ni)
#pragma unroll
      for (int r = 0; r < 4; ++r) {
        float v = acc[mi][ni][r];
        float p = __shfl_xor(v, 1, 64);
        int col = colb + ni * 16 + (lane & 15);
        float gv = (col & 1) ? p : v;
        float uv = (col & 1) ? v : p;
        float hv = gv / (1.f + expf(-gv)) * uv;
        if (!(col & 1)) {
          int row = row0 + wm * 64 + mi * 16 + rquad + r;
          h[(size_t)row * H_ + (col >> 1)] = f2bf(hv);
        }
      }
}

// ---------------- GEMM2 (fast): y = h @ W2^T ----------------
__global__ __launch_bounds__(256) void gemm2_f(
    const unsigned short* __restrict__ hbuf, const unsigned short* __restrict__ W2,
    float* __restrict__ y, const int* __restrict__ meta)
{
  int tile = blockIdx.x;
  if (tile >= meta[ME_NT]) return;
  int ntile = blockIdx.y;  // 0..7 over D
  int e = meta[ME_TE + tile];
  int row0 = meta[ME_TR + tile];

  __shared__ unsigned short As[128 * 64];
  __shared__ unsigned short Bs[128 * 64];

  int t = threadIdx.x, lane = t & 63, w = t >> 6;
  int wm = w >> 1, wn = w & 1;

  const unsigned short* ap = hbuf + ((size_t)row0 + w * 32 + (lane >> 3)) * H_ + (lane & 7) * 8;
  const unsigned short* bp = W2 + ((size_t)e * D_ + ntile * 128 + w * 32 + (lane >> 3)) * H_ + (lane & 7) * 8;
  unsigned short* la = As + (w * 32) * 64;
  unsigned short* lb = Bs + (w * 32) * 64;

  floatx4 acc[4][4];
  floatx4 zero4 = {0.f, 0.f, 0.f, 0.f};
#pragma unroll
  for (int a = 0; a < 4; ++a)
#pragma unroll
    for (int b = 0; b < 4; ++b) acc[a][b] = zero4;

  int mrow = lane & 15, kq = (lane >> 4) * 8;

  for (int k0 = 0; k0 < H_; k0 += 64) {
    __syncthreads();
#pragma unroll
    for (int i = 0; i < 4; ++i) {
      gl_lds16(ap + k0 + i * 8 * H_, la + i * 8 * 64);
      gl_lds16(bp + k0 + i * 8 * H_, lb + i * 8 * 64);
    }
    __syncthreads();
#pragma unroll
    for (int kk = 0; kk < 64; kk += 32) {
      bf16x8 af[4], bfv[4];
#pragma unroll
      for (int mi = 0; mi < 4; ++mi)
        af[mi] = *(const bf16x8*)(As + (wm * 64 + mi * 16 + mrow) * 64 + kk + kq);
#pragma unroll
      for (int ni = 0; ni < 4; ++ni)
        bfv[ni] = *(const bf16x8*)(Bs + (wn * 64 + ni * 16 + mrow) * 64 + kk + kq);
#pragma unroll
      for (int mi = 0; mi < 4; ++mi)
#pragma unroll
        for (int ni = 0; ni < 4; ++ni)
          acc[mi][ni] = __builtin_amdgcn_mfma_f32_16x16x32_bf16(af[mi], bfv[ni], acc[mi][ni], 0, 0, 0);
    }
  }

  int rquad = (lane >> 4) * 4;
  int colb = ntile * 128 + wn * 64;
#pragma unroll
  for (int mi = 0; mi < 4; ++mi)
#pragma unroll
    for (int ni = 0; ni < 4; ++ni)
#pragma unroll
      for (int r = 0; r < 4; ++r) {
        int row = row0 + wm * 64 + mi * 16 + rquad + r;
        y[(size_t)row * D_ + colb + ni * 16 + (lane & 15)] = acc[mi][ni][r];
      }
}

// ---------------- fallback GEMMs (fp32 weights, in-loop pack) ----------------
__global__ __launch_bounds__(256) void gemm1_k(
    const unsigned short* __restrict__ xs,
    const float* __restrict__ wg, const float* __restrict__ wu,
    unsigned short* __restrict__ h, const int* __restrict__ meta)
{
  int tile = blockIdx.x;
  if (tile >= meta[ME_NT]) return;
  int ntile = blockIdx.y;
  int e = meta[ME_TE + tile];
  int row0 = meta[ME_TR + tile];
  __shared__ uint4 As4[512];
  __shared__ uint4 Bg4[512];
  __shared__ uint4 Bu4[512];
  const unsigned short* As = (const unsigned short*)As4;
  const unsigned short* Bg = (const unsigned short*)Bg4;
  const unsigned short* Bu = (const unsigned short*)Bu4;
  int t = threadIdx.x;
  int lane = t & 63, w = t >> 6;
  int wm = w >> 1, wn = w & 1;
  const unsigned short* ap = xs + (size_t)row0 * D_;
  const float* wgp = wg + ((size_t)e * H_ + ntile * 128) * D_;
  const float* wup = wu + ((size_t)e * H_ + ntile * 128) * D_;
  floatx4 zero4 = {0.f, 0.f, 0.f, 0.f};
  floatx4 accg[4][4], accu[4][4];
  for (int a = 0; a < 4; ++a) for (int b = 0; b < 4; ++b) { accg[a][b] = zero4; accu[a][b] = zero4; }
  int bn = t >> 1, bkh = t & 1;
  for (int k0 = 0; k0 < D_; k0 += 32) {
    __syncthreads();
    {
      int c = t;
      As4[c] = *(const uint4*)(ap + (size_t)(c >> 2) * D_ + k0 + (c & 3) * 8);
      c = t + 256;
      As4[c] = *(const uint4*)(ap + (size_t)(c >> 2) * D_ + k0 + (c & 3) * 8);
    }
    {
      const float4* srcg = (const float4*)(wgp + (size_t)bn * D_ + k0 + bkh * 16);
      const float4* srcu = (const float4*)(wup + (size_t)bn * D_ + k0 + bkh * 16);
      float4 g0 = srcg[0], g1 = srcg[1], g2 = srcg[2], g3 = srcg[3];
      float4 u0 = srcu[0], u1 = srcu[1], u2 = srcu[2], u3 = srcu[3];
      int base = bn * 4 + bkh * 2;
      Bg4[base]     = make_uint4(pack2(g0.x, g0.y), pack2(g0.z, g0.w), pack2(g1.x, g1.y), pack2(g1.z, g1.w));
      Bg4[base + 1] = make_uint4(pack2(g2.x, g2.y), pack2(g2.z, g2.w), pack2(g3.x, g3.y), pack2(g3.z, g3.w));
      Bu4[base]     = make_uint4(pack2(u0.x, u0.y), pack2(u0.z, u0.w), pack2(u1.x, u1.y), pack2(u1.z, u1.w));
      Bu4[base + 1] = make_uint4(pack2(u2.x, u2.y), pack2(u2.z, u2.w), pack2(u3.x, u3.y), pack2(u3.z, u3.w));
    }
    __syncthreads();
    int mrow = lane & 15;
    int kq = (lane >> 4) * 8;
    bf16x8 af[4], bg[4], bu[4];
    for (int mi = 0; mi < 4; ++mi)
      af[mi] = *(const bf16x8*)(As + (wm * 64 + mi * 16 + mrow) * 32 + kq);
    for (int ni = 0; ni < 4; ++ni) {
      int r = (wn * 64 + ni * 16 + mrow) * 32 + kq;
      bg[ni] = *(const bf16x8*)(Bg + r);
      bu[ni] = *(const bf16x8*)(Bu + r);
    }
    for (int mi = 0; mi < 4; ++mi)
      for (int ni = 0; ni < 4; ++ni) {
        accg[mi][ni] = __builtin_amdgcn_mfma_f32_16x16x32_bf16(af[mi], bg[ni], accg[mi][ni], 0, 0, 0);
        accu[mi][ni] = __builtin_amdgcn_mfma_f32_16x16x32_bf16(af[mi], bu[ni], accu[mi][ni], 0, 0, 0);
      }
  }
  int colb = ntile * 128 + wn * 64;
  int rquad = (lane >> 4) * 4;
  for (int mi = 0; mi < 4; ++mi)
    for (int ni = 0; ni < 4; ++ni)
      for (int r = 0; r < 4; ++r) {
        int row = row0 + wm * 64 + mi * 16 + rquad + r;
        int col = colb + ni * 16 + (lane & 15);
        float gv = accg[mi][ni][r], uv = accu[mi][ni][r];
        float sv = gv / (1.f + expf(-gv));
        h[(size_t)row * H_ + col] = f2bf(sv * uv);
      }
}

__global__ __launch_bounds__(256) void gemm2_k(
    const unsigned short* __restrict__ hbuf,
    const float* __restrict__ wd,
    float* __restrict__ y, const int* __restrict__ meta)
{
  int tile = blockIdx.x;
  if (tile >= meta[ME_NT]) return;
  int ntile = blockIdx.y;
  int e = meta[ME_TE + tile];
  int row0 = meta[ME_TR + tile];
  __shared__ uint4 As4[512];
  __shared__ uint4 Bd4[512];
  const unsigned short* As = (const unsigned short*)As4;
  const unsigned short* Bd = (const unsigned short*)Bd4;
  int t = threadIdx.x;
  int lane = t & 63, w = t >> 6;
  int wm = w >> 1, wn = w & 1;
  const unsigned short* ap = hbuf + (size_t)row0 * H_;
  const float* wdp = wd + ((size_t)e * D_ + ntile * 128) * H_;
  floatx4 zero4 = {0.f, 0.f, 0.f, 0.f};
  floatx4 acc[4][4];
  for (int a = 0; a < 4; ++a) for (int b = 0; b < 4; ++b) acc[a][b] = zero4;
  int bn = t >> 1, bkh = t & 1;
  for (int k0 = 0; k0 < H_; k0 += 32) {
    __syncthreads();
    {
      int c = t;
      As4[c] = *(const uint4*)(ap + (size_t)(c >> 2) * H_ + k0 + (c & 3) * 8);
      c = t + 256;
      As4[c] = *(const uint4*)(ap + (size_t)(c >> 2) * H_ + k0 + (c & 3) * 8);
    }
    {
      const float4* srcd = (const float4*)(wdp + (size_t)bn * H_ + k0 + bkh * 16);
      float4 d0 = srcd[0], d1 = srcd[1], d2 = srcd[2], d3 = srcd[3];
      int base = bn * 4 + bkh * 2;
      Bd4[base]     = make_uint4(pack2(d0.x, d0.y), pack2(d0.z, d0.w), pack2(d1.x, d1.y), pack2(d1.z, d1.w));
      Bd4[base + 1] = make_uint4(pack2(d2.x, d2.y), pack2(d2.z, d2.w), pack2(d3.x, d3.y), pack2(d3.z, d3.w));
    }
    __syncthreads();
    int mrow = lane & 15;
    int kq = (lane >> 4) * 8;
    bf16x8 af[4], bfv[4];
    for (int mi = 0; mi < 4; ++mi)
      af[mi] = *(const bf16x8*)(As + (wm * 64 + mi * 16 + mrow) * 32 + kq);
    for (int ni = 0; ni < 4; ++ni)
      bfv[ni] = *(const bf16x8*)(Bd + (wn * 64 + ni * 16 + mrow) * 32 + kq);
    for (int mi = 0; mi < 4; ++mi)
      for (int ni = 0; ni < 4; ++ni)
        acc[mi][ni] = __builtin_amdgcn_mfma_f32_16x16x32_bf16(af[mi], bfv[ni], acc[mi][ni], 0, 0, 0);
  }
  int colb = ntile * 128 + wn * 64;
  int rquad = (lane >> 4) * 4;
  for (int mi = 0; mi < 4; ++mi)
    for (int ni = 0; ni < 4; ++ni)
      for (int r = 0; r < 4; ++r) {
        int row = row0 + wm * 64 + mi * 16 + rquad + r;
        int col = colb + ni * 16 + (lane & 15);
        y[(size_t)row * D_ + col] = acc[mi][ni][r];
      }
}

// ---------------- combine ----------------
__global__ __launch_bounds__(256) void combine_k(
    const float* __restrict__ y, const float* __restrict__ rw,
    const int* __restrict__ slot_of, float* __restrict__ out)
{
  int s = blockIdx.x, t = threadIdx.x;
  int s0 = slot_of[s * 2], s1 = slot_of[s * 2 + 1];
  float w0 = rw[s * 2], w1 = rw[s * 2 + 1];
  float4 a = ((const float4*)(y + (size_t)s0 * D_))[t];
  float4 b = ((const float4*)(y + (size_t)s1 * D_))[t];
  float4 o;
  o.x = w0 * a.x + w1 * b.x;
  o.y = w0 * a.y + w1 * b.y;
  o.z = w0 * a.z + w1 * b.z;
  o.w = w0 * a.w + w1 * b.w;
  ((float4*)(out + (size_t)s * D_))[t] = o;
}

extern "C" void kernel_launch(void* const* d_in, const int* in_sizes, int n_in,
                              void* d_out, int out_size, void* d_ws, size_t ws_size,
                              hipStream_t stream) {
  const float* x  = (const float*)d_in[0];
  const float* gw = (const float*)d_in[1];
  const float* wg = (const float*)d_in[2];
  const float* wu = (const float*)d_in[3];
  const float* wd = (const float*)d_in[4];

  float* out = (float*)d_out;
  float* logits_out = out + (size_t)S_ * D_;
  float* topi_out = logits_out + (size_t)S_ * E_;

  char* ws = (char*)d_ws;
  int* meta = (int*)(ws + WS_META);
  int* slot_of = (int*)(ws + WS_SLOT);
  float* rw = (float*)(ws + WS_RW);
  int* topi = (int*)(ws + WS_TOPI);
  unsigned short* xs = (unsigned short*)(ws + WS_XS);
  float* y = (float*)(ws + WS_XS);            // overlays xs (dead after gemm1)
  unsigned short* h = (unsigned short*)(ws + WS_H);
  unsigned short* W1 = (unsigned short*)(ws + WS_W);
  unsigned short* W2 = W1;                    // wd-bf16 overlays W1 (dead after gemm1)

  hipMemsetAsync(meta, 0, 4096, stream);
  hipMemsetAsync(xs, 0, (size_t)MP_ * D_ * 2, stream);  // zero pad rows

  router_k<<<S_, 256, 0, stream>>>(x, gw, logits_out, topi_out, rw, topi, meta);
  scan_k<<<1, 64, 0, stream>>>(meta);
  scatter_k<<<(S_ * K_ + 255) / 256, 256, 0, stream>>>(topi, meta, slot_of);
  gather_k<<<S_ * K_, 256, 0, stream>>>(x, slot_of, xs);

  if (ws_size >= WS_NEED) {
    convert_gu_k<<<dim3(H2_, E_), 128, 0, stream>>>(wg, wu, W1);
    gemm1_f<<<dim3(MAXT, H2_ / 128), 256, 0, stream>>>(xs, W1, h, meta);
    convert_d_k<<<(E_ * D_ * H_ / 8) / 256, 256, 0, stream>>>(wd, W2);
    gemm2_f<<<dim3(MAXT, D_ / 128), 256, 0, stream>>>(h, W2, y, meta);
  } else {
    gemm1_k<<<dim3(MAXT, H_ / 128), 256, 0, stream>>>(xs, wg, wu, h, meta);
    gemm2_k<<<dim3(MAXT, D_ / 128), 256, 0, stream>>>(h, wd, y, meta);
  }
  combine_k<<<S_, 256, 0, stream>>>(y, rw, slot_of, out);
}